// Round 3
// baseline (432.155 us; speedup 1.0000x reference)
//
#include <hip/hip_runtime.h>
#include <cstdint>

#define B_ 8
#define T_ 4096
#define TP1 4097
#define IN_ 512
#define H_ 512
#define N3H 1536
#define KD 1024
#define CHUNKS 64
#define CLEN 64   // T_/CHUNKS
#define NT 16     // KD/64 K-tiles

typedef __attribute__((ext_vector_type(4))) float floatx4;
typedef __attribute__((ext_vector_type(16))) float floatx16;
typedef __attribute__((ext_vector_type(4))) float f4;
typedef __attribute__((ext_vector_type(8))) short short8;
typedef __attribute__((ext_vector_type(4))) unsigned short us4;
typedef __attribute__((ext_vector_type(4))) _Float16 h4;

#define Z16 {0.f,0.f,0.f,0.f,0.f,0.f,0.f,0.f,0.f,0.f,0.f,0.f,0.f,0.f,0.f,0.f}

__device__ __forceinline__ unsigned short f2bf(float v){
  unsigned int u = __float_as_uint(v);
  unsigned int r = (u + 0x7fffu + ((u >> 16) & 1u)) >> 16;
  return (unsigned short)r;
}
// fast sigmoid: one v_exp_f32 + one v_rcp_f32 (no IEEE div sequence)
__device__ __forceinline__ float sigm(float x){
  return __builtin_amdgcn_rcpf(1.f + __expf(-x));
}
__device__ __forceinline__ float tanhf_(float x){ return 2.f*sigm(2.f*x) - 1.f; }

#define GLLS(src, dst) __builtin_amdgcn_global_load_lds( \
    (const __attribute__((address_space(1))) void*)(src), \
    (__attribute__((address_space(3))) void*)(dst), 16, 0, 0)

// x f32 [B,T,IN] -> xpad bf16 [B, T+1, IN] with zero row at t'=0 (causal pad)
__global__ void cast_pad_kernel(const float* __restrict__ x, unsigned short* __restrict__ xpad){
  int64_t i = (int64_t)blockIdx.x*256 + threadIdx.x;       // over B*TP1*(IN/4)
  const int64_t total = (int64_t)B_*TP1*(IN_/4);
  if (i >= total) return;
  int cg = (int)(i & 127);
  int64_t r = i >> 7;                                      // row (b*TP1 + t)
  int t = (int)(r % TP1);
  int b = (int)(r / TP1);
  us4 o;
  if (t == 0){ o = (us4){0,0,0,0}; }
  else {
    f4 v = *(const f4*)(x + ((int64_t)b*T_ + (t-1))*IN_ + cg*4);
    #pragma unroll
    for (int u=0;u<4;++u) o[u] = f2bf(v[u]);
  }
  *(us4*)(xpad + r*IN_ + cg*4) = o;
}

// w f32 [3H, IN, K=2] -> wt bf16 [3H, 1024], k-major halves; blockIdx.y picks layer
__global__ void wt_kernel(const float* __restrict__ wA, unsigned short* __restrict__ wtA,
                          const float* __restrict__ wB, unsigned short* __restrict__ wtB){
  int i = blockIdx.x*256 + threadIdx.x;                    // over N3H*512
  if (i >= N3H*512) return;
  const float* w = blockIdx.y ? wB : wA;
  unsigned short* wt = blockIdx.y ? wtB : wtA;
  int ci = i & 511;
  int o = i >> 9;
  const float* wp = w + (int64_t)o*KD + ci*2;
  wt[(int64_t)o*KD + ci]       = f2bf(wp[0]);
  wt[(int64_t)o*KD + 512 + ci] = f2bf(wp[1]);
}

// ---------------------------------------------------------------------------
// 256x256x64 8-phase GEMM, 32x32x16 MFMA variant (2382 TF pipe vs 2075 for
// 16x16x32; half the MFMA instruction count). Staging/swizzle/vmcnt/barrier
// schedule identical to the verified 16x16 version.
// Fragment maps: A/B row=lane&31, k=(lane>>5)*8+e (ext. of verified 16x16 map);
// C/D col=lane&31, row=(reg&3)+8*(reg>>2)+4*(lane>>5)  [HW-verified m74/m101].
// LDS (shorts): A: d*16384 + half*8192 + row*64 + physSlot*8 ; B: +32768.
//   physSlot = logicalSlot ^ (row&7); GLLS writes linearly, swizzle applied by
//   pre-permuting the per-lane GLOBAL source slot (lcol ^ lrow).
// ---------------------------------------------------------------------------
#define MFMA32(a,b,c) __builtin_amdgcn_mfma_f32_32x32x16_bf16(a,b,c,0,0,0)
#define BAR() __builtin_amdgcn_s_barrier()

#define ST_A(tt, h) do { \
    const unsigned short* _s = aSrc + (h)*128*IN_ + (tt)*64; \
    unsigned short* _d = smem + ((tt)&1)*16384 + (h)*8192 + dstBase; \
    GLLS(_s, _d); GLLS(_s + 64*IN_, _d + 4096); } while(0)
#define ST_B(tt, h) do { \
    const unsigned short* _s = bSrc + (h)*128*KD + (tt)*64; \
    unsigned short* _d = smem + 32768 + ((tt)&1)*16384 + (h)*8192 + dstBase; \
    GLLS(_s, _d); GLLS(_s + 64*KD, _d + 4096); } while(0)

// mh: M-half (0/1) -> LDS half; ml: 32-row sub-block within wave's 64 rows
#define LDA32(d,mh,ml,j) (*(const short8*)(smem + (d)*16384 + (mh)*8192 + (ml)*2048 + aBase + sw[j]))
#define LDB32(d,n,j)     (*(const short8*)(smem + 32768 + (d)*16384 + (n)*8192 + bBase + sw[j]))

#define TILE(tc, SA1, SB1, SA0, SB0, VMN) do { \
  const int d_ = (tc) & 1; \
  /* q0: read A half0 (m-frags 0,1) + B n0; stage A1(t+1) */ \
  _Pragma("unroll") for (int j=0;j<4;++j){ aF0[j]=LDA32(d_,0,0,j); aF1[j]=LDA32(d_,0,1,j); bF0[j]=LDB32(d_,0,j); } \
  if (SA1) ST_A((tc)+1, 1); \
  BAR(); \
  __builtin_amdgcn_s_setprio(1); \
  _Pragma("unroll") for (int j=0;j<4;++j){ acc00=MFMA32(aF0[j],bF0[j],acc00); acc10=MFMA32(aF1[j],bF0[j],acc10); } \
  __builtin_amdgcn_s_setprio(0); \
  BAR(); \
  /* q1: read B n1; stage B1(t+1) */ \
  _Pragma("unroll") for (int j=0;j<4;++j){ bF1[j]=LDB32(d_,1,j); } \
  if (SB1) ST_B((tc)+1, 1); \
  BAR(); \
  __builtin_amdgcn_s_setprio(1); \
  _Pragma("unroll") for (int j=0;j<4;++j){ acc01=MFMA32(aF0[j],bF1[j],acc01); acc11=MFMA32(aF1[j],bF1[j],acc11); } \
  __builtin_amdgcn_s_setprio(0); \
  BAR(); \
  /* q2: read A half1 (m-frags 2,3); stage A0(t+2) */ \
  _Pragma("unroll") for (int j=0;j<4;++j){ aF0[j]=LDA32(d_,1,0,j); aF1[j]=LDA32(d_,1,1,j); } \
  if (SA0) ST_A((tc)+2, 0); \
  BAR(); \
  __builtin_amdgcn_s_setprio(1); \
  _Pragma("unroll") for (int j=0;j<4;++j){ acc20=MFMA32(aF0[j],bF0[j],acc20); acc30=MFMA32(aF1[j],bF0[j],acc30); } \
  __builtin_amdgcn_s_setprio(0); \
  BAR(); \
  /* q3: stage B0(t+2); MFMA half1 x n1; counted vmcnt at tile boundary */ \
  if (SB0) ST_B((tc)+2, 0); \
  BAR(); \
  __builtin_amdgcn_s_setprio(1); \
  _Pragma("unroll") for (int j=0;j<4;++j){ acc21=MFMA32(aF0[j],bF1[j],acc21); acc31=MFMA32(aF1[j],bF1[j],acc31); } \
  __builtin_amdgcn_s_setprio(0); \
  if ((VMN)==4) asm volatile("s_waitcnt vmcnt(4)" ::: "memory"); \
  else if ((VMN)==0) asm volatile("s_waitcnt vmcnt(0)" ::: "memory"); \
  BAR(); \
} while(0)

#define EPI(accv, mf, n) do { \
  const int rowb = m0 + wm*64 + ((mf)&1)*32 + ((mf)>>1)*128 + hh*4; \
  const int col  = n0 + wn*32 + (n)*128 + r32; \
  _Float16* cp = C + (int64_t)rowb*N3H + col; \
  _Pragma("unroll") for (int reg=0;reg<16;++reg){ \
    const int rofs = (reg&3) + 8*(reg>>2); \
    float v = accv[reg] + bv[n]; \
    v = (act == 0) ? tanhf_(v) : sigm(v); \
    cp[(int64_t)rofs*N3H] = (_Float16)v; \
  } \
} while(0)

__global__ __launch_bounds__(512, 2) void gemm_kernel(
    const unsigned short* __restrict__ A, const unsigned short* __restrict__ W,
    const float* __restrict__ bias, _Float16* __restrict__ C){
  __shared__ unsigned short smem[65536];   // 128 KiB: A [0,32768), B [32768,65536)
  const int tid  = threadIdx.x;
  const int lane = tid & 63;
  const int wave = tid >> 6;
  const int r32  = lane & 31;
  const int hh   = lane >> 5;
  const int wm = wave >> 2;      // 0..1 (M)
  const int wn = wave & 3;       // 0..3 (N)
  const int lrow = lane >> 3;    // 0..7
  const int lcol = lane & 7;     // 0..7

  // XCD-bijective chunked swizzle (768 = 8 xcd * 96); m-major / n-inner per chunk
  const int bid = blockIdx.x;
  const int wg = (bid & 7) * 96 + (bid >> 3);
  const int mt = wg / 6;
  const int nt = wg % 6;
  const int m0 = mt * 256;
  const int n0 = nt * 256;
  const int bb = m0 / T_;               // tile fully inside one batch (256 | 4096)
  const int act = n0 >> 9;              // 0=z(tanh), 1=f(sigm), 2=o(sigm)

  // staging: lane writes LDS linearly (row = wave*8+lrow, slot = lcol);
  // source slot pre-swizzled so LDS physSlot p holds logical p^(row&7)
  const unsigned short* aSrc = A + (int64_t)(m0 + bb + wave*8 + lrow)*IN_ + (lcol ^ lrow)*8;
  const unsigned short* bSrc = W + (int64_t)(n0 + wave*8 + lrow)*KD + (lcol ^ lrow)*8;
  const int dstBase = (wave*8 + lrow)*64 + lcol*8;   // shorts; == lane*16B per wave

  // ds_read bases (shorts); per-kstep swizzled slot offsets
  const int aBase = (wm*64 + r32)*64;
  const int bBase = (wn*32 + r32)*64;
  int sw[4];
  #pragma unroll
  for (int j=0;j<4;++j) sw[j] = ((2*j + hh) ^ (r32 & 7)) * 8;

  floatx16 acc00 = Z16, acc01 = Z16, acc10 = Z16, acc11 = Z16;
  floatx16 acc20 = Z16, acc21 = Z16, acc30 = Z16, acc31 = Z16;
  short8 aF0[4], aF1[4], bF0[4], bF1[4];

  // prologue: tile0 {A0,B0,A1,B1} + tile1 {A0,B0}; allow last 2 half-tiles in flight
  ST_A(0,0); ST_B(0,0); ST_A(0,1); ST_B(0,1); ST_A(1,0); ST_B(1,0);
  asm volatile("s_waitcnt vmcnt(4)" ::: "memory");
  BAR();

  #pragma unroll 2
  for (int t = 0; t < NT-2; ++t){
    TILE(t, 1, 1, 1, 1, 4);
  }
  TILE(NT-2, 1, 1, 0, 0, 0);
  TILE(NT-1, 0, 0, 0, 0, -1);

  // epilogue: bias + activation, f16 store
  float bv[2];
  #pragma unroll
  for (int n=0;n<2;++n) bv[n] = bias[n0 + wn*32 + n*128 + r32];
  EPI(acc00, 0, 0); EPI(acc01, 0, 1);
  EPI(acc10, 1, 0); EPI(acc11, 1, 1);
  EPI(acc20, 2, 0); EPI(acc21, 2, 1);
  EPI(acc30, 3, 0); EPI(acc31, 3, 1);
}

// phase 1: per-chunk affine composition (Aa, Bb): h_out = Aa*h_in + Bb
__global__ void scan_phase1(const _Float16* __restrict__ conv,
                            float* __restrict__ carA, float* __restrict__ carB){
  int q = blockIdx.x*256 + threadIdx.x;     // CHUNKS*8*128 = 65536
  int chg = q & 127;
  int bq = (q >> 7) & 7;
  int c  = q >> 10;
  int ch = chg*4;
  f4 Aa = {1.f,1.f,1.f,1.f}, Bb = {0.f,0.f,0.f,0.f};
  const _Float16* p = conv + ((int64_t)bq*T_ + c*CLEN)*N3H + ch;
  for (int g=0; g<CLEN/8; ++g){
    h4 zb[8], fb[8];
    #pragma unroll
    for (int u=0;u<8;++u){
      zb[u] = *(const h4*)(p + (int64_t)u*N3H);
      fb[u] = *(const h4*)(p + (int64_t)u*N3H + 512);
    }
    #pragma unroll
    for (int u=0;u<8;++u){
      #pragma unroll
      for (int v=0;v<4;++v){
        float fv = (float)fb[u][v];
        float zv = (float)zb[u][v];
        Aa[v] *= fv;
        Bb[v] = fv*Bb[v] + (1.f-fv)*zv;
      }
    }
    p += (int64_t)8*N3H;
  }
  *(f4*)(carA + (int64_t)q*4) = Aa;
  *(f4*)(carB + (int64_t)q*4) = Bb;
}

// phase 2: scan over chunks; emit h at chunk starts + final hT. 1 channel/thread.
__global__ void scan_phase2(const float* __restrict__ carA, const float* __restrict__ carB,
                            float* __restrict__ hstart, float* __restrict__ hT){
  int q = blockIdx.x*256 + threadIdx.x;     // 4096 channels (b*512+ch)
  float h = 0.f;
  for (int c=0;c<CHUNKS;++c){
    int64_t idx = (int64_t)c*4096 + q;
    hstart[idx] = h;
    h = carA[idx]*h + carB[idx];
  }
  hT[q] = h;
}

// phase 3: replay chunk with true h-start, apply o*h, write output
template<int LAYER>
__global__ void scan_phase3(const _Float16* __restrict__ conv,
                            const float* __restrict__ hstart, unsigned short* __restrict__ xpad,
                            float* __restrict__ outf){
  int q = blockIdx.x*256 + threadIdx.x;     // 65536
  int chg = q & 127;
  int bq = (q >> 7) & 7;
  int c  = q >> 10;
  int ch = chg*4;
  f4 h;
  #pragma unroll
  for (int v=0;v<4;++v) h[v] = hstart[(int64_t)c*4096 + bq*512 + ch + v];
  const _Float16* p = conv + ((int64_t)bq*T_ + c*CLEN)*N3H + ch;
  int t = c*CLEN;
  for (int g=0; g<CLEN/8; ++g){
    h4 zb[8], fb[8], ob[8];
    #pragma unroll
    for (int u=0;u<8;++u){
      zb[u] = *(const h4*)(p + (int64_t)u*N3H);
      fb[u] = *(const h4*)(p + (int64_t)u*N3H + 512);
      ob[u] = *(const h4*)(p + (int64_t)u*N3H + 1024);
    }
    #pragma unroll
    for (int u=0;u<8;++u){
      if (LAYER == 0){
        us4 ov4;
        #pragma unroll
        for (int v=0;v<4;++v){
          float fv = (float)fb[u][v];
          h[v] = fv*h[v] + (1.f-fv)*(float)zb[u][v];
          ov4[v] = f2bf((float)ob[u][v]*h[v]);
        }
        *(us4*)(xpad + ((int64_t)bq*TP1 + t+u + 1)*IN_ + ch) = ov4;
      } else {
        f4 of4;
        #pragma unroll
        for (int v=0;v<4;++v){
          float fv = (float)fb[u][v];
          h[v] = fv*h[v] + (1.f-fv)*(float)zb[u][v];
          of4[v] = (float)ob[u][v]*h[v];
        }
        *(f4*)(outf + ((int64_t)bq*T_ + t+u)*H_ + ch) = of4;
      }
    }
    t += 8; p += (int64_t)8*N3H;
  }
}

extern "C" void kernel_launch(void* const* d_in, const int* in_sizes, int n_in,
                              void* d_out, int out_size, void* d_ws, size_t ws_size,
                              hipStream_t stream){
  const float* x  = (const float*)d_in[0];
  const float* w0 = (const float*)d_in[1];
  const float* b0 = (const float*)d_in[2];
  const float* w1 = (const float*)d_in[3];
  const float* b1 = (const float*)d_in[4];
  float* out = (float*)d_out;

  char* ws = (char*)d_ws;
  size_t off = 0;
  auto alloc = [&](size_t bytes)->char*{
    char* p = ws + off; off = (off + bytes + 255) & ~(size_t)255; return p; };
  unsigned short* xpad = (unsigned short*)alloc((size_t)B_*TP1*IN_*2);
  unsigned short* Wt0  = (unsigned short*)alloc((size_t)N3H*KD*2);
  unsigned short* Wt1  = (unsigned short*)alloc((size_t)N3H*KD*2);
  _Float16* conv = (_Float16*)alloc((size_t)B_*T_*N3H*2);
  float* carA = (float*)alloc((size_t)CHUNKS*4096*4);
  float* carB = (float*)alloc((size_t)CHUNKS*4096*4);
  float* hst  = (float*)alloc((size_t)CHUNKS*4096*4);
  if (off > ws_size) return;  // workspace too small -> fail loudly in validation

  float* out_main = out;
  float* h0 = out + (int64_t)B_*T_*H_;
  float* h1 = h0 + B_*H_;

  const int64_t padN = (int64_t)B_*TP1*(IN_/4);
  cast_pad_kernel<<<(int)((padN + 255)/256), 256, 0, stream>>>(x, xpad);
  dim3 wgrid((N3H*512 + 255)/256, 2);
  wt_kernel<<<wgrid, 256, 0, stream>>>(w0, Wt0, w1, Wt1);

  const int ggrid = ((B_*T_)/256) * (N3H/256);   // 128*6 = 768
  const int sgrid = (CHUNKS*8*128) / 256;        // 256
  gemm_kernel<<<ggrid, 512, 0, stream>>>(xpad, Wt0, b0, conv);
  scan_phase1<<<sgrid, 256, 0, stream>>>(conv, carA, carB);
  scan_phase2<<<16, 256, 0, stream>>>(carA, carB, hst, h0);
  scan_phase3<0><<<sgrid, 256, 0, stream>>>(conv, hst, xpad, nullptr);

  gemm_kernel<<<ggrid, 512, 0, stream>>>(xpad, Wt1, b1, conv);
  scan_phase1<<<sgrid, 256, 0, stream>>>(conv, carA, carB);
  scan_phase2<<<16, 256, 0, stream>>>(carA, carB, hst, h1);
  scan_phase3<1><<<sgrid, 256, 0, stream>>>(conv, hst, nullptr, out_main);
}